// Round 3
// baseline (1654.400 us; speedup 1.0000x reference)
//
#include <hip/hip_runtime.h>
#include <hip/hip_bf16.h>

typedef __hip_bfloat16 bf16;
typedef __attribute__((ext_vector_type(8))) __bf16 bf16x8;
typedef __attribute__((ext_vector_type(4))) float f32x4;
typedef __attribute__((ext_vector_type(16))) float f32x16;
typedef __attribute__((ext_vector_type(4))) unsigned short us4;
typedef __attribute__((ext_vector_type(8))) unsigned short us8;

__device__ inline unsigned short f2bf(float f) {
    __hip_bfloat16 h = __float2bfloat16(f);
    return __builtin_bit_cast(unsigned short, h);
}

__device__ inline void block_reduce_atomic(float v, float* dst) {
    #pragma unroll
    for (int o = 32; o > 0; o >>= 1) v += __shfl_down(v, o, 64);
    __shared__ float ws[8];
    const int lane = threadIdx.x & 63;
    const int wid  = threadIdx.x >> 6;
    if (lane == 0) ws[wid] = v;
    __syncthreads();
    if (threadIdx.x == 0) {
        float s = 0.f;
        const int nw = (blockDim.x + 63) >> 6;
        for (int i = 0; i < nw; ++i) s += ws[i];
        atomicAdd(dst, s);
    }
}

// ---------------------------------------------------------------------------
// small kernels
// ---------------------------------------------------------------------------
__global__ void zero_accs_kernel(float* accs) {
    if (threadIdx.x < 8) accs[threadIdx.x] = 0.f;
}

__global__ void mse_kernel(const float* __restrict__ a, const float* __restrict__ b,
                           float* __restrict__ acc, int n) {
    float s = 0.f;
    for (int i = blockIdx.x * blockDim.x + threadIdx.x; i < n; i += gridDim.x * blockDim.x) {
        float d = a[i] - b[i];
        s += d * d;
    }
    block_reduce_atomic(s, acc);
}

__global__ void ssim_kernel(const float* __restrict__ x, const float* __restrict__ y,
                            float* __restrict__ acc) {
    const int b = blockIdx.y;
    const int t = blockIdx.x * blockDim.x + threadIdx.x;
    float S = 0.f;
    if (t < 250 * 250) {
        const int i = t / 250, j = t - (t / 250) * 250;
        const float* xp = x + (size_t)b * 65536;
        const float* yp = y + (size_t)b * 65536;
        float sx = 0.f, sy = 0.f, sxx = 0.f, syy = 0.f, sxy = 0.f;
        #pragma unroll
        for (int dy = 0; dy < 7; ++dy) {
            const float* xr = xp + (size_t)(i + dy) * 256 + j;
            const float* yr = yp + (size_t)(i + dy) * 256 + j;
            #pragma unroll
            for (int dx = 0; dx < 7; ++dx) {
                float a = xr[dx], c = yr[dx];
                sx += a; sy += c;
                sxx += a * a; syy += c * c; sxy += a * c;
            }
        }
        const float inv = 1.f / 49.f;
        const float cn  = 49.f / 48.f;
        float ux = sx * inv, uy = sy * inv;
        float vx  = cn * (sxx * inv - ux * ux);
        float vy  = cn * (syy * inv - uy * uy);
        float vxy = cn * (sxy * inv - ux * uy);
        const float C1 = 1e-4f, C2 = 9e-4f;
        S = ((2.f * ux * uy + C1) * (2.f * vxy + C2)) /
            ((ux * ux + uy * uy + C1) * (vx + vy + C2));
    }
    block_reduce_atomic(S, acc);
}

__global__ void sqdiff_kernel(const bf16* __restrict__ a, const bf16* __restrict__ b,
                              float* __restrict__ acc, int n) {
    float s = 0.f;
    for (int i = blockIdx.x * blockDim.x + threadIdx.x; i < n; i += gridDim.x * blockDim.x) {
        float d = __bfloat162float(a[i]) - __bfloat162float(b[i]);
        s += d * d;
    }
    block_reduce_atomic(s, acc);
}

__global__ void finalize_kernel(const float* __restrict__ accs, float* __restrict__ out) {
    if (threadIdx.x == 0) {
        float mse    = accs[0] * (1.f / 524288.f);
        float ssim_l = 1.f - accs[1] * (1.f / 500000.f);
        float perc   = accs[2] * (1.f / 33554432.f);
        out[0] = mse + 0.5f * ssim_l + 0.1f * perc;
        out[1] = mse;
        out[2] = ssim_l;
        out[3] = perc;
    }
}

// repack weights (CO,CIN,3,3) fp32 -> (CO, 9, CIN) bf16
__global__ void wprep_kernel(const float* __restrict__ w, bf16* __restrict__ wb,
                             int CIN, int CO) {
    int idx = blockIdx.x * blockDim.x + threadIdx.x;
    int n = CO * 9 * CIN;
    if (idx >= n) return;
    int ci = idx % CIN;
    int t  = (idx / CIN) % 9;
    int co = idx / (9 * CIN);
    wb[idx] = __float2bfloat16(w[((size_t)co * CIN + ci) * 9 + t]);
}

// ---------------------------------------------------------------------------
// conv1: CIN=1, CO=64, fp32 NCHW in -> bf16 NHWC out, relu
// ---------------------------------------------------------------------------
__global__ __launch_bounds__(256) void conv1_kernel(
    const float* __restrict__ sr, const float* __restrict__ hr, int nb, int b0,
    const float* __restrict__ w, const float* __restrict__ bias,
    bf16* __restrict__ out) {
    const int H = 256, W = 256;
    const int img = blockIdx.y;
    const float* in = (img < nb) ? (sr + (size_t)(b0 + img) * 65536)
                                 : (hr + (size_t)(b0 + img - nb) * 65536);
    int px = blockIdx.x * 256 + threadIdx.x;
    int y = px >> 8, x = px & 255;
    float p[9];
    #pragma unroll
    for (int dy = 0; dy < 3; ++dy)
        #pragma unroll
        for (int dx = 0; dx < 3; ++dx) {
            int gy = y + dy - 1, gx = x + dx - 1;
            float v = 0.f;
            if ((unsigned)gy < (unsigned)H && (unsigned)gx < (unsigned)W)
                v = in[(size_t)gy * W + gx];
            p[dy * 3 + dx] = v;
        }
    bf16* op = out + ((size_t)img * H * W + px) * 64;
    #pragma unroll
    for (int c8 = 0; c8 < 8; ++c8) {
        us8 o;
        #pragma unroll
        for (int c = 0; c < 8; ++c) {
            int co = c8 * 8 + c;
            float a = bias[co];
            #pragma unroll
            for (int k = 0; k < 9; ++k) a += w[co * 9 + k] * p[k];
            o[c] = f2bf(fmaxf(a, 0.f));
        }
        *(us8*)(op + c8 * 8) = o;
    }
}

// ---------------------------------------------------------------------------
// implicit-GEMM 3x3 SAME conv, NHWC bf16 -> NHWC bf16, bias+relu,
// 32x32x16 MFMA. block: 4 waves (wm: co half, wn: y half).
// block tile: 128 co x (8y x 16x) px. wave tile: 64 co x 64 px (2 mt x 2 nt).
// LDS: 10x18 halo patch x CSTEP ch, pixel stride CSTEP*2+16 (pad).
// A-frags (weights) for all 9 taps hoisted per K16 step (72 VGPR).
// POOL: fused 2x2 maxpool epilogue via shfl_xor lanes 16 (y) and 1 (x).
// ---------------------------------------------------------------------------
template <int CIN, int CSTEP, bool POOL>
__global__ __launch_bounds__(256) void conv_mfma2(
    const bf16* __restrict__ in,    // (NIMG, H, W, CIN)
    const bf16* __restrict__ wb,    // (CO, 9, CIN)
    const float* __restrict__ bias, // (CO)
    bf16* __restrict__ out,         // NHWC (pooled dims if POOL)
    int H, int W, int CO) {
    const int tid  = threadIdx.x;
    const int lane = tid & 63;
    const int wave = tid >> 6;
    const int wm = wave & 1, wn = wave >> 1;
    const int xl = lane & 15;
    const int yy = (lane >> 4) & 1;
    const int kh = lane >> 5;
    const int x0 = blockIdx.x * 16;
    const int y0 = blockIdx.y * 8;
    const int nco = CO >> 7;
    const int img = blockIdx.z / nco;
    const int co0 = (blockIdx.z - img * nco) << 7;

    constexpr int PSTR = CSTEP * 2 + 16;
    __shared__ __align__(16) char smem[10 * 18 * PSTR];

    f32x16 acc[2][2];
    #pragma unroll
    for (int m = 0; m < 2; ++m)
        #pragma unroll
        for (int n = 0; n < 2; ++n)
            #pragma unroll
            for (int r = 0; r < 16; ++r) acc[m][n][r] = 0.f;

    const bf16* inp = in + (size_t)img * H * W * CIN;

    // weights A-frag lane base (tap-centered at t=4): m = lane&31 = co row
    const int coA = co0 + wm * 64 + (lane & 31);
    const bf16* ap0 = wb + ((size_t)coA * 9 + 4) * CIN + kh * 8;

    // B lane LDS byte base (nt=0, dy=dx=0, k16=0)
    const int boff = ((wn * 4 + yy) * 18 + xl) * PSTR + kh * 16;

    for (int cbase = 0; cbase < CIN; cbase += CSTEP) {
        if (cbase) __syncthreads();
        // ---- stage 10x18xCSTEP halo patch ----
        constexpr int QN  = CSTEP / 8;       // 16B chunks per pixel
        constexpr int NCH = 10 * 18 * QN;
        for (int c = tid; c < NCH; c += 256) {
            int q = c & (QN - 1);
            int p = c / QN;
            int px = p % 18, row = p / 18;
            int gy = y0 - 1 + row, gx = x0 - 1 + px;
            uint4 v = {0u, 0u, 0u, 0u};
            if ((unsigned)gy < (unsigned)H && (unsigned)gx < (unsigned)W)
                v = *(const uint4*)(inp + ((size_t)gy * W + gx) * CIN + cbase + q * 8);
            *(uint4*)(smem + (row * 18 + px) * PSTR + q * 16) = v;
        }
        __syncthreads();

        for (int k16 = 0; k16 < CSTEP; k16 += 16) {
            const bf16* aK = ap0 + cbase + k16;
            bf16x8 A[9][2];
            #pragma unroll
            for (int t = 0; t < 9; ++t) {
                A[t][0] = *(const bf16x8*)(aK + (t - 4) * CIN);
                A[t][1] = *(const bf16x8*)(aK + (size_t)32 * 9 * CIN + (t - 4) * CIN);
            }
            const char* bK = smem + boff + k16 * 2;
            #pragma unroll
            for (int t = 0; t < 9; ++t) {
                const int dy = t / 3, dx = t - dy * 3;
                bf16x8 b0 = *(const bf16x8*)(bK + ((0 + dy) * 18 + dx) * PSTR);
                bf16x8 b1 = *(const bf16x8*)(bK + ((2 + dy) * 18 + dx) * PSTR);
                acc[0][0] = __builtin_amdgcn_mfma_f32_32x32x16_bf16(A[t][0], b0, acc[0][0], 0, 0, 0);
                acc[1][0] = __builtin_amdgcn_mfma_f32_32x32x16_bf16(A[t][1], b0, acc[1][0], 0, 0, 0);
                acc[0][1] = __builtin_amdgcn_mfma_f32_32x32x16_bf16(A[t][0], b1, acc[0][1], 0, 0, 0);
                acc[1][1] = __builtin_amdgcn_mfma_f32_32x32x16_bf16(A[t][1], b1, acc[1][1], 0, 0, 0);
            }
        }
    }

    // ---- epilogue ----
    // C/D layout: col(pixel) = lane&31 (x = xl, y-sub = yy), row(co within 32)
    // = (reg&3) + 8*(reg>>2) + 4*kh.
    if (!POOL) {
        #pragma unroll
        for (int m = 0; m < 2; ++m)
            #pragma unroll
            for (int nt = 0; nt < 2; ++nt) {
                const int y = y0 + wn * 4 + nt * 2 + yy;
                const size_t pxo = ((size_t)img * H + y) * W + (x0 + xl);
                #pragma unroll
                for (int g = 0; g < 4; ++g) {
                    const int co = co0 + wm * 64 + m * 32 + g * 8 + kh * 4;
                    const f32x4 bv = *(const f32x4*)(bias + co);
                    us4 o;
                    #pragma unroll
                    for (int r = 0; r < 4; ++r)
                        o[r] = f2bf(fmaxf(acc[m][nt][g * 4 + r] + bv[r], 0.f));
                    *(us4*)(out + pxo * CO + co) = o;
                }
            }
    } else {
        const int Wp = W >> 1;
        #pragma unroll
        for (int m = 0; m < 2; ++m)
            #pragma unroll
            for (int nt = 0; nt < 2; ++nt) {
                #pragma unroll
                for (int g = 0; g < 4; ++g) {
                    const int co = co0 + wm * 64 + m * 32 + g * 8 + kh * 4;
                    const f32x4 bv = *(const f32x4*)(bias + co);
                    float vv[4];
                    #pragma unroll
                    for (int r = 0; r < 4; ++r) {
                        float v = fmaxf(acc[m][nt][g * 4 + r] + bv[r], 0.f);
                        float t1 = fmaxf(v, __shfl_xor(v, 16));   // fold yy
                        vv[r] = fmaxf(t1, __shfl_xor(t1, 1));     // fold x pair
                    }
                    if ((lane & 0x11) == 0) {
                        const int py = (y0 >> 1) + wn * 2 + nt;
                        const int px = (x0 >> 1) + (xl >> 1);
                        us4 o;
                        #pragma unroll
                        for (int r = 0; r < 4; ++r) o[r] = f2bf(vv[r]);
                        *(us4*)(out + (((size_t)img * (H >> 1) + py) * Wp + px) * CO + co) = o;
                    }
                }
            }
    }
}

// ---------------------------------------------------------------------------
// launch
// ---------------------------------------------------------------------------
extern "C" void kernel_launch(void* const* d_in, const int* in_sizes, int n_in,
                              void* d_out, int out_size, void* d_ws, size_t ws_size,
                              hipStream_t stream) {
    const float* sr = (const float*)d_in[0];
    const float* hr = (const float*)d_in[1];
    const float* w1 = (const float*)d_in[2];
    const float* b1 = (const float*)d_in[3];
    const float* w2 = (const float*)d_in[4];
    const float* b2 = (const float*)d_in[5];
    const float* w3 = (const float*)d_in[6];
    const float* b3 = (const float*)d_in[7];
    const float* w4 = (const float*)d_in[8];
    const float* b4 = (const float*)d_in[9];
    float* out = (float*)d_out;

    char* ws = (char*)d_ws;
    size_t off = 0;
    float* accs = (float*)(ws + off); off += 256;
    bf16* wb2 = (bf16*)(ws + off); off += (size_t)128 * 9 * 64 * 2;
    bf16* wb3 = (bf16*)(ws + off); off += (size_t)256 * 9 * 128 * 2;
    bf16* wb4 = (bf16*)(ws + off); off += (size_t)256 * 9 * 256 * 2;
    const size_t fixed = (off + 255) & ~(size_t)255;

    const size_t MB = 1024u * 1024u;
    // per image: A 8MB, P 4MB, G 8MB, F 8MB = 28MB; chunk = 2*nb images
    int nb = 8;
    while (nb > 1 && fixed + (size_t)nb * 2 * 28 * MB > ws_size) nb >>= 1;

    bf16* A = (bf16*)(ws + fixed);                                   // (ni,256,256,64)
    bf16* P = (bf16*)(ws + fixed + (size_t)nb * 2 * 8 * MB);         // (ni,128,128,128)
    bf16* G = (bf16*)(ws + fixed + (size_t)nb * 2 * 12 * MB);        // (ni,128,128,256)
    bf16* F = (bf16*)(ws + fixed + (size_t)nb * 2 * 20 * MB);        // (ni,128,128,256)

    zero_accs_kernel<<<1, 32, 0, stream>>>(accs);
    wprep_kernel<<<288, 256, 0, stream>>>(w2, wb2, 64, 128);
    wprep_kernel<<<1152, 256, 0, stream>>>(w3, wb3, 128, 256);
    wprep_kernel<<<2304, 256, 0, stream>>>(w4, wb4, 256, 256);
    mse_kernel<<<2048, 256, 0, stream>>>(sr, hr, accs + 0, 524288);
    ssim_kernel<<<dim3(245, 8), 256, 0, stream>>>(sr, hr, accs + 1);

    for (int b0 = 0; b0 < 8; b0 += nb) {
        const int ni = 2 * nb;  // sr images then hr images
        conv1_kernel<<<dim3(256, ni), 256, 0, stream>>>(sr, hr, nb, b0, w1, b1, A);
        // conv2 + fused pool -> P
        conv_mfma2<64, 64, true><<<dim3(16, 32, ni), 256, 0, stream>>>(
            A, wb2, b2, P, 256, 256, 128);
        // conv3 -> G
        conv_mfma2<128, 128, false><<<dim3(8, 16, ni * 2), 256, 0, stream>>>(
            P, wb3, b3, G, 128, 128, 256);
        // conv4 -> F
        conv_mfma2<256, 128, false><<<dim3(8, 16, ni * 2), 256, 0, stream>>>(
            G, wb4, b4, F, 128, 128, 256);
        // perceptual partial
        sqdiff_kernel<<<4096, 256, 0, stream>>>(
            F, F + (size_t)nb * 4194304, accs + 2, nb * 4194304);
    }

    finalize_kernel<<<1, 1, 0, stream>>>(accs, out);
}

// Round 4
// 1032.139 us; speedup vs baseline: 1.6029x; 1.6029x over previous
//
#include <hip/hip_runtime.h>
#include <hip/hip_bf16.h>

typedef __hip_bfloat16 bf16;
typedef __attribute__((ext_vector_type(8))) __bf16 bf16x8;
typedef __attribute__((ext_vector_type(4))) float f32x4;
typedef __attribute__((ext_vector_type(16))) float f32x16;
typedef __attribute__((ext_vector_type(4))) unsigned short us4;
typedef __attribute__((ext_vector_type(8))) unsigned short us8;

__device__ inline unsigned short f2bf(float f) {
    __hip_bfloat16 h = __float2bfloat16(f);
    return __builtin_bit_cast(unsigned short, h);
}
__device__ inline float bf2f(unsigned short u) {
    unsigned int x = ((unsigned int)u) << 16;
    return __builtin_bit_cast(float, x);
}

__device__ inline void block_reduce_atomic(float v, float* dst) {
    #pragma unroll
    for (int o = 32; o > 0; o >>= 1) v += __shfl_down(v, o, 64);
    __shared__ float ws[8];
    const int lane = threadIdx.x & 63;
    const int wid  = threadIdx.x >> 6;
    if (lane == 0) ws[wid] = v;
    __syncthreads();
    if (threadIdx.x == 0) {
        float s = 0.f;
        const int nw = (blockDim.x + 63) >> 6;
        for (int i = 0; i < nw; ++i) s += ws[i];
        atomicAdd(dst, s);
    }
}

// ---------------------------------------------------------------------------
// small kernels
// ---------------------------------------------------------------------------
__global__ void zero_accs_kernel(float* accs) {
    if (threadIdx.x < 8) accs[threadIdx.x] = 0.f;
}

__global__ void mse_kernel(const float* __restrict__ a, const float* __restrict__ b,
                           float* __restrict__ acc, int n) {
    float s = 0.f;
    for (int i = blockIdx.x * blockDim.x + threadIdx.x; i < n; i += gridDim.x * blockDim.x) {
        float d = a[i] - b[i];
        s += d * d;
    }
    block_reduce_atomic(s, acc);
}

__global__ void ssim_kernel(const float* __restrict__ x, const float* __restrict__ y,
                            float* __restrict__ acc) {
    const int b = blockIdx.y;
    const int t = blockIdx.x * blockDim.x + threadIdx.x;
    float S = 0.f;
    if (t < 250 * 250) {
        const int i = t / 250, j = t - (t / 250) * 250;
        const float* xp = x + (size_t)b * 65536;
        const float* yp = y + (size_t)b * 65536;
        float sx = 0.f, sy = 0.f, sxx = 0.f, syy = 0.f, sxy = 0.f;
        #pragma unroll
        for (int dy = 0; dy < 7; ++dy) {
            const float* xr = xp + (size_t)(i + dy) * 256 + j;
            const float* yr = yp + (size_t)(i + dy) * 256 + j;
            #pragma unroll
            for (int dx = 0; dx < 7; ++dx) {
                float a = xr[dx], c = yr[dx];
                sx += a; sy += c;
                sxx += a * a; syy += c * c; sxy += a * c;
            }
        }
        const float inv = 1.f / 49.f;
        const float cn  = 49.f / 48.f;
        float ux = sx * inv, uy = sy * inv;
        float vx  = cn * (sxx * inv - ux * ux);
        float vy  = cn * (syy * inv - uy * uy);
        float vxy = cn * (sxy * inv - ux * uy);
        const float C1 = 1e-4f, C2 = 9e-4f;
        S = ((2.f * ux * uy + C1) * (2.f * vxy + C2)) /
            ((ux * ux + uy * uy + C1) * (vx + vy + C2));
    }
    block_reduce_atomic(S, acc);
}

// vectorized 16B/lane squared-diff reduction over bf16
__global__ void sqdiff8_kernel(const us8* __restrict__ a, const us8* __restrict__ b,
                               float* __restrict__ acc, int n8) {
    float s = 0.f;
    for (int i = blockIdx.x * blockDim.x + threadIdx.x; i < n8; i += gridDim.x * blockDim.x) {
        us8 va = a[i], vb = b[i];
        #pragma unroll
        for (int k = 0; k < 8; ++k) {
            float d = bf2f(va[k]) - bf2f(vb[k]);
            s += d * d;
        }
    }
    block_reduce_atomic(s, acc);
}

__global__ void finalize_kernel(const float* __restrict__ accs, float* __restrict__ out) {
    if (threadIdx.x == 0) {
        float mse    = accs[0] * (1.f / 524288.f);
        float ssim_l = 1.f - accs[1] * (1.f / 500000.f);
        float perc   = accs[2] * (1.f / 33554432.f);
        out[0] = mse + 0.5f * ssim_l + 0.1f * perc;
        out[1] = mse;
        out[2] = ssim_l;
        out[3] = perc;
    }
}

// repack weights (CO,CIN,3,3) fp32 -> (CO, 9, CIN) bf16
__global__ void wprep_kernel(const float* __restrict__ w, bf16* __restrict__ wb,
                             int CIN, int CO) {
    int idx = blockIdx.x * blockDim.x + threadIdx.x;
    int n = CO * 9 * CIN;
    if (idx >= n) return;
    int ci = idx % CIN;
    int t  = (idx / CIN) % 9;
    int co = idx / (9 * CIN);
    wb[idx] = __float2bfloat16(w[((size_t)co * CIN + ci) * 9 + t]);
}

// ---------------------------------------------------------------------------
// conv1: CIN=1, CO=64, fp32 NCHW in -> bf16 NHWC out, relu
// ---------------------------------------------------------------------------
__global__ __launch_bounds__(256) void conv1_kernel(
    const float* __restrict__ sr, const float* __restrict__ hr, int nb, int b0,
    const float* __restrict__ w, const float* __restrict__ bias,
    bf16* __restrict__ out) {
    const int H = 256, W = 256;
    const int img = blockIdx.y;
    const float* in = (img < nb) ? (sr + (size_t)(b0 + img) * 65536)
                                 : (hr + (size_t)(b0 + img - nb) * 65536);
    int px = blockIdx.x * 256 + threadIdx.x;
    int y = px >> 8, x = px & 255;
    float p[9];
    #pragma unroll
    for (int dy = 0; dy < 3; ++dy)
        #pragma unroll
        for (int dx = 0; dx < 3; ++dx) {
            int gy = y + dy - 1, gx = x + dx - 1;
            float v = 0.f;
            if ((unsigned)gy < (unsigned)H && (unsigned)gx < (unsigned)W)
                v = in[(size_t)gy * W + gx];
            p[dy * 3 + dx] = v;
        }
    bf16* op = out + ((size_t)img * H * W + px) * 64;
    #pragma unroll
    for (int c8 = 0; c8 < 8; ++c8) {
        us8 o;
        #pragma unroll
        for (int c = 0; c < 8; ++c) {
            int co = c8 * 8 + c;
            float a = bias[co];
            #pragma unroll
            for (int k = 0; k < 9; ++k) a += w[co * 9 + k] * p[k];
            o[c] = f2bf(fmaxf(a, 0.f));
        }
        *(us8*)(op + c8 * 8) = o;
    }
}

// ---------------------------------------------------------------------------
// implicit-GEMM 3x3 SAME conv, NHWC bf16 -> NHWC bf16, bias+relu, 32x32x16.
// Block: 4 waves, tile = 64 co x (16y x 16x) px; every wave same 64 co,
// wave wn covers a 4-row y strip; wave tile m2 x n2 = 64co x 64px.
// Per k16 phase, BOTH operands staged in LDS:
//   act patch: 18x18 px x 16ch, 48 B/px stride (conflict-free b128)
//   weights:   64co x 9tap x 16k, 304 B/co stride (2-way = free)
// Staging addresses precomputed in registers; both advance 32 B per phase.
// POOL: fused 2x2 maxpool epilogue via shfl_xor 16 (y) and 1 (x).
// ---------------------------------------------------------------------------
#define ACT_BYTES (18 * 18 * 48)          // 15552
#define WT_OFF    ACT_BYTES
#define WT_BYTES  (64 * 304)              // 19456

template <int CIN, bool POOL>
__global__ __launch_bounds__(256, 4) void conv_mfma3(
    const bf16* __restrict__ in,    // (NIMG, H, W, CIN)
    const bf16* __restrict__ wb,    // (CO, 9, CIN)
    const float* __restrict__ bias, // (CO)
    bf16* __restrict__ out,         // NHWC (pooled dims if POOL)
    int H, int W, int CO) {
    const int tid  = threadIdx.x;
    const int lane = tid & 63;
    const int wn   = tid >> 6;          // y strip
    const int xl = lane & 15;
    const int yy = (lane >> 4) & 1;
    const int kh = lane >> 5;
    const int x0 = blockIdx.x * 16;
    const int y0 = blockIdx.y * 16;
    const int ngrp = CO >> 6;
    const int img = blockIdx.z / ngrp;
    const int co0 = (blockIdx.z - img * ngrp) << 6;

    __shared__ __align__(16) char smem[ACT_BYTES + WT_BYTES];

    f32x16 acc[2][2];
    #pragma unroll
    for (int m = 0; m < 2; ++m)
        #pragma unroll
        for (int n = 0; n < 2; ++n)
            #pragma unroll
            for (int r = 0; r < 16; ++r) acc[m][n][r] = 0.f;

    const bf16* inp = in + (size_t)img * H * W * CIN;

    // ---- precompute staging descriptors (8 chunks/thread, phase-invariant) ----
    const char* srcp[8];
    int dsto[8];
    #pragma unroll
    for (int i = 0; i < 8; ++i) {
        int c = tid + i * 256;
        srcp[i] = nullptr;
        dsto[i] = -1;
        if (c < 648) {                       // act: 18*18 px * 2 chunks
            int q = c & 1, p = c >> 1;
            int row = p / 18, col = p - row * 18;
            int gy = y0 - 1 + row, gx = x0 - 1 + col;
            dsto[i] = p * 48 + q * 16;
            if ((unsigned)gy < (unsigned)H && (unsigned)gx < (unsigned)W)
                srcp[i] = (const char*)(inp + ((size_t)gy * W + gx) * CIN) + q * 16;
        } else if (c < 1800) {               // wt: 64co * 9tap * 2 chunks
            int c2 = c - 648;
            int q = c2 & 1, u = c2 >> 1;
            int co = u / 9, t = u - co * 9;
            dsto[i] = WT_OFF + co * 304 + t * 32 + q * 16;
            srcp[i] = (const char*)(wb + ((size_t)(co0 + co) * 9 + t) * CIN) + q * 16;
        }
    }

    // per-lane LDS read bases
    const char* awt  = smem + WT_OFF + (lane & 31) * 304 + kh * 16;
    const char* bact = smem + (((wn * 4 + yy) * 18) + xl) * 48 + kh * 16;

    for (int cb = 0; cb < CIN; cb += 16) {
        if (cb) __syncthreads();
        #pragma unroll
        for (int i = 0; i < 8; ++i) {
            if (dsto[i] >= 0) {
                uint4 v = {0u, 0u, 0u, 0u};
                if (srcp[i]) { v = *(const uint4*)srcp[i]; srcp[i] += 32; }
                *(uint4*)(smem + dsto[i]) = v;
            }
        }
        __syncthreads();

        #pragma unroll
        for (int t = 0; t < 9; ++t) {
            const int dy = t / 3, dx = t - dy * 3;
            bf16x8 A0 = *(const bf16x8*)(awt + t * 32);
            bf16x8 A1 = *(const bf16x8*)(awt + 32 * 304 + t * 32);
            bf16x8 B0 = *(const bf16x8*)(bact + ((0 + dy) * 18 + dx) * 48);
            bf16x8 B1 = *(const bf16x8*)(bact + ((2 + dy) * 18 + dx) * 48);
            acc[0][0] = __builtin_amdgcn_mfma_f32_32x32x16_bf16(A0, B0, acc[0][0], 0, 0, 0);
            acc[1][0] = __builtin_amdgcn_mfma_f32_32x32x16_bf16(A1, B0, acc[1][0], 0, 0, 0);
            acc[0][1] = __builtin_amdgcn_mfma_f32_32x32x16_bf16(A0, B1, acc[0][1], 0, 0, 0);
            acc[1][1] = __builtin_amdgcn_mfma_f32_32x32x16_bf16(A1, B1, acc[1][1], 0, 0, 0);
        }
    }

    // ---- epilogue ----
    // C/D (verified): col(pixel) = lane&31 -> (yy, xl); row(co in 32) =
    // (reg&3) + 8*(reg>>2) + 4*kh.
    if (!POOL) {
        #pragma unroll
        for (int m = 0; m < 2; ++m)
            #pragma unroll
            for (int nt = 0; nt < 2; ++nt) {
                const int y = y0 + wn * 4 + nt * 2 + yy;
                bf16* op = out + (((size_t)img * H + y) * W + (x0 + xl)) * CO;
                #pragma unroll
                for (int g = 0; g < 4; ++g) {
                    const int co = co0 + m * 32 + g * 8 + kh * 4;
                    const f32x4 bv = *(const f32x4*)(bias + co);
                    us4 o;
                    #pragma unroll
                    for (int r = 0; r < 4; ++r)
                        o[r] = f2bf(fmaxf(acc[m][nt][g * 4 + r] + bv[r], 0.f));
                    *(us4*)(op + co) = o;
                }
            }
    } else {
        const int Hp = H >> 1, Wp = W >> 1;
        #pragma unroll
        for (int m = 0; m < 2; ++m)
            #pragma unroll
            for (int nt = 0; nt < 2; ++nt) {
                #pragma unroll
                for (int g = 0; g < 4; ++g) {
                    const int co = co0 + m * 32 + g * 8 + kh * 4;
                    const f32x4 bv = *(const f32x4*)(bias + co);
                    float vv[4];
                    #pragma unroll
                    for (int r = 0; r < 4; ++r) {
                        float v = fmaxf(acc[m][nt][g * 4 + r] + bv[r], 0.f);
                        float t1 = fmaxf(v, __shfl_xor(v, 16));   // fold yy
                        vv[r] = fmaxf(t1, __shfl_xor(t1, 1));     // fold x pair
                    }
                    if ((lane & 0x11) == 0) {
                        const int py = (y0 >> 1) + wn * 2 + nt;
                        const int px = (x0 >> 1) + (xl >> 1);
                        us4 o;
                        #pragma unroll
                        for (int r = 0; r < 4; ++r) o[r] = f2bf(vv[r]);
                        *(us4*)(out + (((size_t)img * Hp + py) * Wp + px) * CO + co) = o;
                    }
                }
            }
    }
}

// ---------------------------------------------------------------------------
// launch
// ---------------------------------------------------------------------------
extern "C" void kernel_launch(void* const* d_in, const int* in_sizes, int n_in,
                              void* d_out, int out_size, void* d_ws, size_t ws_size,
                              hipStream_t stream) {
    const float* sr = (const float*)d_in[0];
    const float* hr = (const float*)d_in[1];
    const float* w1 = (const float*)d_in[2];
    const float* b1 = (const float*)d_in[3];
    const float* w2 = (const float*)d_in[4];
    const float* b2 = (const float*)d_in[5];
    const float* w3 = (const float*)d_in[6];
    const float* b3 = (const float*)d_in[7];
    const float* w4 = (const float*)d_in[8];
    const float* b4 = (const float*)d_in[9];
    float* out = (float*)d_out;

    char* ws = (char*)d_ws;
    size_t off = 0;
    float* accs = (float*)(ws + off); off += 256;
    bf16* wb2 = (bf16*)(ws + off); off += (size_t)128 * 9 * 64 * 2;
    bf16* wb3 = (bf16*)(ws + off); off += (size_t)256 * 9 * 128 * 2;
    bf16* wb4 = (bf16*)(ws + off); off += (size_t)256 * 9 * 256 * 2;
    const size_t fixed = (off + 255) & ~(size_t)255;

    const size_t MB = 1024u * 1024u;
    // per image: A 8MB, P 4MB, G 8MB, F 8MB = 28MB; chunk = 2*nb images
    int nb = 8;
    while (nb > 1 && fixed + (size_t)nb * 2 * 28 * MB > ws_size) nb >>= 1;

    bf16* A = (bf16*)(ws + fixed);                                   // (ni,256,256,64)
    bf16* P = (bf16*)(ws + fixed + (size_t)nb * 2 * 8 * MB);         // (ni,128,128,128)
    bf16* G = (bf16*)(ws + fixed + (size_t)nb * 2 * 12 * MB);        // (ni,128,128,256)
    bf16* F = (bf16*)(ws + fixed + (size_t)nb * 2 * 20 * MB);        // (ni,128,128,256)

    zero_accs_kernel<<<1, 32, 0, stream>>>(accs);
    wprep_kernel<<<288, 256, 0, stream>>>(w2, wb2, 64, 128);
    wprep_kernel<<<1152, 256, 0, stream>>>(w3, wb3, 128, 256);
    wprep_kernel<<<2304, 256, 0, stream>>>(w4, wb4, 256, 256);
    mse_kernel<<<2048, 256, 0, stream>>>(sr, hr, accs + 0, 524288);
    ssim_kernel<<<dim3(245, 8), 256, 0, stream>>>(sr, hr, accs + 1);

    for (int b0 = 0; b0 < 8; b0 += nb) {
        const int ni = 2 * nb;  // sr images then hr images
        conv1_kernel<<<dim3(256, ni), 256, 0, stream>>>(sr, hr, nb, b0, w1, b1, A);
        // conv2 + fused pool -> P
        conv_mfma3<64, true><<<dim3(16, 16, ni * 2), 256, 0, stream>>>(
            A, wb2, b2, P, 256, 256, 128);
        // conv3 -> G
        conv_mfma3<128, false><<<dim3(8, 8, ni * 4), 256, 0, stream>>>(
            P, wb3, b3, G, 128, 128, 256);
        // conv4 -> F
        conv_mfma3<256, false><<<dim3(8, 8, ni * 4), 256, 0, stream>>>(
            G, wb4, b4, F, 128, 128, 256);
        // perceptual partial (16B/lane)
        sqdiff8_kernel<<<4096, 256, 0, stream>>>(
            (const us8*)F, (const us8*)(F + (size_t)nb * 4194304), accs + 2,
            nb * 524288);
    }

    finalize_kernel<<<1, 1, 0, stream>>>(accs, out);
}

// Round 5
// 911.145 us; speedup vs baseline: 1.8157x; 1.1328x over previous
//
#include <hip/hip_runtime.h>
#include <hip/hip_bf16.h>

typedef __hip_bfloat16 bf16;
typedef __attribute__((ext_vector_type(8))) __bf16 bf16x8;
typedef __attribute__((ext_vector_type(4))) float f32x4;
typedef __attribute__((ext_vector_type(16))) float f32x16;
typedef __attribute__((ext_vector_type(4))) unsigned short us4;
typedef __attribute__((ext_vector_type(8))) unsigned short us8;

__device__ inline unsigned short f2bf(float f) {
    __hip_bfloat16 h = __float2bfloat16(f);
    return __builtin_bit_cast(unsigned short, h);
}
__device__ inline float bf2f(unsigned short u) {
    unsigned int x = ((unsigned int)u) << 16;
    return __builtin_bit_cast(float, x);
}

// async global->LDS 16B copy; LDS dst must be wave-uniform base + lane*16
typedef __attribute__((address_space(3))) unsigned int lds_uint;
typedef __attribute__((address_space(1))) const unsigned int g_uint;
__device__ inline void gload_lds16(const void* g, void* l) {
    __builtin_amdgcn_global_load_lds((g_uint*)g, (lds_uint*)l, 16, 0, 0);
}

__device__ inline void block_reduce_atomic(float v, float* dst) {
    #pragma unroll
    for (int o = 32; o > 0; o >>= 1) v += __shfl_down(v, o, 64);
    __shared__ float ws[8];
    const int lane = threadIdx.x & 63;
    const int wid  = threadIdx.x >> 6;
    if (lane == 0) ws[wid] = v;
    __syncthreads();
    if (threadIdx.x == 0) {
        float s = 0.f;
        const int nw = (blockDim.x + 63) >> 6;
        for (int i = 0; i < nw; ++i) s += ws[i];
        atomicAdd(dst, s);
    }
}

// ---------------------------------------------------------------------------
// small kernels
// ---------------------------------------------------------------------------
__global__ void zero_accs_kernel(float* accs, float* zbuf) {
    if (threadIdx.x < 8)  accs[threadIdx.x] = 0.f;
    if (threadIdx.x < 64) zbuf[threadIdx.x] = 0.f;
}

__global__ void mse_kernel(const float* __restrict__ a, const float* __restrict__ b,
                           float* __restrict__ acc, int n) {
    float s = 0.f;
    for (int i = blockIdx.x * blockDim.x + threadIdx.x; i < n; i += gridDim.x * blockDim.x) {
        float d = a[i] - b[i];
        s += d * d;
    }
    block_reduce_atomic(s, acc);
}

__global__ void ssim_kernel(const float* __restrict__ x, const float* __restrict__ y,
                            float* __restrict__ acc) {
    const int b = blockIdx.y;
    const int t = blockIdx.x * blockDim.x + threadIdx.x;
    float S = 0.f;
    if (t < 250 * 250) {
        const int i = t / 250, j = t - (t / 250) * 250;
        const float* xp = x + (size_t)b * 65536;
        const float* yp = y + (size_t)b * 65536;
        float sx = 0.f, sy = 0.f, sxx = 0.f, syy = 0.f, sxy = 0.f;
        #pragma unroll
        for (int dy = 0; dy < 7; ++dy) {
            const float* xr = xp + (size_t)(i + dy) * 256 + j;
            const float* yr = yp + (size_t)(i + dy) * 256 + j;
            #pragma unroll
            for (int dx = 0; dx < 7; ++dx) {
                float a = xr[dx], c = yr[dx];
                sx += a; sy += c;
                sxx += a * a; syy += c * c; sxy += a * c;
            }
        }
        const float inv = 1.f / 49.f;
        const float cn  = 49.f / 48.f;
        float ux = sx * inv, uy = sy * inv;
        float vx  = cn * (sxx * inv - ux * ux);
        float vy  = cn * (syy * inv - uy * uy);
        float vxy = cn * (sxy * inv - ux * uy);
        const float C1 = 1e-4f, C2 = 9e-4f;
        S = ((2.f * ux * uy + C1) * (2.f * vxy + C2)) /
            ((ux * ux + uy * uy + C1) * (vx + vy + C2));
    }
    block_reduce_atomic(S, acc);
}

__global__ void finalize_kernel(const float* __restrict__ accs, float* __restrict__ out) {
    if (threadIdx.x == 0) {
        float mse    = accs[0] * (1.f / 524288.f);
        float ssim_l = 1.f - accs[1] * (1.f / 500000.f);
        float perc   = accs[2] * (1.f / 33554432.f);
        out[0] = mse + 0.5f * ssim_l + 0.1f * perc;
        out[1] = mse;
        out[2] = ssim_l;
        out[3] = perc;
    }
}

// repack weights (CO,CIN,3,3) fp32 -> (CO, 9, CIN) bf16
__global__ void wprep_kernel(const float* __restrict__ w, bf16* __restrict__ wb,
                             int CIN, int CO) {
    int idx = blockIdx.x * blockDim.x + threadIdx.x;
    int n = CO * 9 * CIN;
    if (idx >= n) return;
    int ci = idx % CIN;
    int t  = (idx / CIN) % 9;
    int co = idx / (9 * CIN);
    wb[idx] = __float2bfloat16(w[((size_t)co * CIN + ci) * 9 + t]);
}

// ---------------------------------------------------------------------------
// conv1: CIN=1, CO=64, fp32 NCHW in -> bf16 NHWC out, relu
// ---------------------------------------------------------------------------
__global__ __launch_bounds__(256) void conv1_kernel(
    const float* __restrict__ in0, const float* __restrict__ w,
    const float* __restrict__ bias, bf16* __restrict__ out) {
    const int H = 256, W = 256;
    const int img = blockIdx.y;
    const float* in = in0 + (size_t)img * 65536;
    int px = blockIdx.x * 256 + threadIdx.x;
    int y = px >> 8, x = px & 255;
    float p[9];
    #pragma unroll
    for (int dy = 0; dy < 3; ++dy)
        #pragma unroll
        for (int dx = 0; dx < 3; ++dx) {
            int gy = y + dy - 1, gx = x + dx - 1;
            float v = 0.f;
            if ((unsigned)gy < (unsigned)H && (unsigned)gx < (unsigned)W)
                v = in[(size_t)gy * W + gx];
            p[dy * 3 + dx] = v;
        }
    bf16* op = out + ((size_t)img * H * W + px) * 64;
    #pragma unroll
    for (int c8 = 0; c8 < 8; ++c8) {
        us8 o;
        #pragma unroll
        for (int c = 0; c < 8; ++c) {
            int co = c8 * 8 + c;
            float a = bias[co];
            #pragma unroll
            for (int k = 0; k < 9; ++k) a += w[co * 9 + k] * p[k];
            o[c] = f2bf(fmaxf(a, 0.f));
        }
        *(us8*)(op + c8 * 8) = o;
    }
}

// ---------------------------------------------------------------------------
// implicit-GEMM 3x3 SAME conv, NHWC bf16 -> NHWC bf16, 32x32x16 MFMA.
// Block: 4 waves; block tile = 64 co x (32y x 16x). Wave wn: rows wn*8..+7,
// wave tile m2 x n4 = 64 co x 128 px -> per tap: 2 A + 4 B ds_read_b128
// feed 8 MFMA (LDS:MFMA = 0.75, 576 MFMA-cyc per barrier).
// LDS (all 16B-chunk-linear in tid -> global_load_lds staging):
//   act: 2 planes (k-half) x 34x18 px x 16 B          = 19584 B
//   wt : [tap][kq][co] 9 x 2 x 64 x 16 B              = 18432 B
// OOB halo chunks load from a zeroed global scratch line.
// EPI: 0 = bias+relu store, 1 = +fused 2x2 maxpool, 2 = bias+relu then
// fused perceptual sum((x - fref)^2) accumulation (no store).
// ---------------------------------------------------------------------------
#define ACT_PLANE (34 * 18 * 16)     // 9792
#define WT_OFF    (2 * ACT_PLANE)    // 19584
#define N_ACT_CH  1224               // 2*34*18
#define N_CHUNK   2376               // act + 9*2*64 wt
#define SMEM_SZ   40960              // 2560 chunks (10 slots * 256 thr)

template <int CIN, int EPI>
__global__ __launch_bounds__(256, 2) void conv_mfma4(
    const bf16* __restrict__ in,     // (NIMG, H, W, CIN)
    const bf16* __restrict__ wb,     // (CO, 9, CIN)
    const float* __restrict__ bias,  // (CO)
    bf16* __restrict__ out,          // NHWC (pooled dims if EPI==1)
    int H, int W, int CO,
    const float* __restrict__ zbuf,  // 64B zeroed scratch
    const bf16* __restrict__ fref,   // EPI==2: reference features
    float* __restrict__ pacc) {      // EPI==2: perceptual accumulator
    const int tid  = threadIdx.x;
    const int lane = tid & 63;
    const int wn   = tid >> 6;           // y strip (8 rows)
    const int xl = lane & 15;
    const int yy = (lane >> 4) & 1;
    const int kh = lane >> 5;
    const int x0 = blockIdx.x * 16;
    const int y0 = blockIdx.y * 32;
    const int ngrp = CO >> 6;
    const int img = blockIdx.z / ngrp;
    const int co0 = (blockIdx.z - img * ngrp) << 6;

    __shared__ __align__(16) char smem[SMEM_SZ];

    f32x16 acc[2][4];
    #pragma unroll
    for (int m = 0; m < 2; ++m)
        #pragma unroll
        for (int n = 0; n < 4; ++n)
            #pragma unroll
            for (int r = 0; r < 16; ++r) acc[m][n][r] = 0.f;

    const bf16* inp = in + (size_t)img * H * W * CIN;

    // ---- phase-invariant staging sources (dst = smem + (tid + i*256)*16) ----
    const char* srcp[10];
    unsigned live = 0;
    #pragma unroll
    for (int i = 0; i < 10; ++i) {
        int c = tid + i * 256;
        srcp[i] = (const char*)zbuf;
        if (c < N_ACT_CH) {
            int q = c / 612, p = c - q * 612;
            int py = p / 18, px = p - py * 18;
            int gy = y0 - 1 + py, gx = x0 - 1 + px;
            if ((unsigned)gy < (unsigned)H && (unsigned)gx < (unsigned)W) {
                srcp[i] = (const char*)(inp + ((size_t)gy * W + gx) * CIN + q * 8);
                live |= 1u << i;
            }
        } else if (c < N_CHUNK) {
            int c2 = c - N_ACT_CH;
            int t = c2 >> 7, q = (c2 >> 6) & 1, co = c2 & 63;
            srcp[i] = (const char*)(wb + ((size_t)(co0 + co) * 9 + t) * CIN + q * 8);
            live |= 1u << i;
        }
    }

    // per-lane LDS read bases
    const char* awt  = smem + WT_OFF + kh * 1024 + (lane & 31) * 16;
    const char* bact = smem + kh * ACT_PLANE + ((wn * 8 + yy) * 18 + xl) * 16;
    char* dst = smem + tid * 16;

    for (int cb = 0; cb < CIN; cb += 16) {
        if (cb) __syncthreads();
        #pragma unroll
        for (int i = 0; i < 10; ++i) {
            gload_lds16(srcp[i], dst + i * 4096);
            if (live & (1u << i)) srcp[i] += 32;
        }
        __syncthreads();

        #pragma unroll
        for (int t = 0; t < 9; ++t) {
            const int dy = t / 3, dx = t - dy * 3;
            bf16x8 A0 = *(const bf16x8*)(awt + t * 2048);
            bf16x8 A1 = *(const bf16x8*)(awt + t * 2048 + 512);
            bf16x8 B[4];
            #pragma unroll
            for (int nt = 0; nt < 4; ++nt)
                B[nt] = *(const bf16x8*)(bact + ((nt * 2 + dy) * 18 + dx) * 16);
            #pragma unroll
            for (int nt = 0; nt < 4; ++nt)
                acc[0][nt] = __builtin_amdgcn_mfma_f32_32x32x16_bf16(A0, B[nt], acc[0][nt], 0, 0, 0);
            #pragma unroll
            for (int nt = 0; nt < 4; ++nt)
                acc[1][nt] = __builtin_amdgcn_mfma_f32_32x32x16_bf16(A1, B[nt], acc[1][nt], 0, 0, 0);
        }
    }

    // ---- epilogue ----
    // C/D (verified): col(pixel) = lane&31 -> (yy, xl); row(co within 32) =
    // (reg&3) + 8*(reg>>2) + 4*kh.
    if (EPI == 0) {
        #pragma unroll
        for (int m = 0; m < 2; ++m)
            #pragma unroll
            for (int nt = 0; nt < 4; ++nt) {
                const int y = y0 + wn * 8 + nt * 2 + yy;
                bf16* op = out + (((size_t)img * H + y) * W + (x0 + xl)) * CO;
                #pragma unroll
                for (int g = 0; g < 4; ++g) {
                    const int co = co0 + m * 32 + g * 8 + kh * 4;
                    const f32x4 bv = *(const f32x4*)(bias + co);
                    us4 o;
                    #pragma unroll
                    for (int r = 0; r < 4; ++r)
                        o[r] = f2bf(fmaxf(acc[m][nt][g * 4 + r] + bv[r], 0.f));
                    *(us4*)(op + co) = o;
                }
            }
    } else if (EPI == 1) {
        const int Hp = H >> 1, Wp = W >> 1;
        #pragma unroll
        for (int m = 0; m < 2; ++m)
            #pragma unroll
            for (int nt = 0; nt < 4; ++nt) {
                #pragma unroll
                for (int g = 0; g < 4; ++g) {
                    const int co = co0 + m * 32 + g * 8 + kh * 4;
                    const f32x4 bv = *(const f32x4*)(bias + co);
                    float vv[4];
                    #pragma unroll
                    for (int r = 0; r < 4; ++r) {
                        float v = fmaxf(acc[m][nt][g * 4 + r] + bv[r], 0.f);
                        float t1 = fmaxf(v, __shfl_xor(v, 16));   // fold yy
                        vv[r] = fmaxf(t1, __shfl_xor(t1, 1));     // fold x pair
                    }
                    if ((lane & 0x11) == 0) {
                        const int py = (y0 >> 1) + wn * 4 + nt;
                        const int px = (x0 >> 1) + (xl >> 1);
                        us4 o;
                        #pragma unroll
                        for (int r = 0; r < 4; ++r) o[r] = f2bf(vv[r]);
                        *(us4*)(out + (((size_t)img * Hp + py) * Wp + px) * CO + co) = o;
                    }
                }
            }
    } else {
        float s = 0.f;
        #pragma unroll
        for (int m = 0; m < 2; ++m)
            #pragma unroll
            for (int nt = 0; nt < 4; ++nt) {
                const int y = y0 + wn * 8 + nt * 2 + yy;
                const bf16* fp = fref + (((size_t)img * H + y) * W + (x0 + xl)) * CO;
                #pragma unroll
                for (int g = 0; g < 4; ++g) {
                    const int co = co0 + m * 32 + g * 8 + kh * 4;
                    const f32x4 bv = *(const f32x4*)(bias + co);
                    us4 f = *(const us4*)(fp + co);
                    #pragma unroll
                    for (int r = 0; r < 4; ++r) {
                        float v = fmaxf(acc[m][nt][g * 4 + r] + bv[r], 0.f);
                        float d = bf2f(f2bf(v)) - bf2f(f[r]);
                        s += d * d;
                    }
                }
            }
        block_reduce_atomic(s, pacc);
    }
}

// ---------------------------------------------------------------------------
// launch
// ---------------------------------------------------------------------------
extern "C" void kernel_launch(void* const* d_in, const int* in_sizes, int n_in,
                              void* d_out, int out_size, void* d_ws, size_t ws_size,
                              hipStream_t stream) {
    const float* sr = (const float*)d_in[0];
    const float* hr = (const float*)d_in[1];
    const float* w1 = (const float*)d_in[2];
    const float* b1 = (const float*)d_in[3];
    const float* w2 = (const float*)d_in[4];
    const float* b2 = (const float*)d_in[5];
    const float* w3 = (const float*)d_in[6];
    const float* b3 = (const float*)d_in[7];
    const float* w4 = (const float*)d_in[8];
    const float* b4 = (const float*)d_in[9];
    float* out = (float*)d_out;

    char* ws = (char*)d_ws;
    size_t off = 0;
    float* accs = (float*)(ws + off); off += 256;
    float* zbuf = (float*)(ws + off); off += 256;
    bf16* wb2 = (bf16*)(ws + off); off += (size_t)128 * 9 * 64 * 2;
    bf16* wb3 = (bf16*)(ws + off); off += (size_t)256 * 9 * 128 * 2;
    bf16* wb4 = (bf16*)(ws + off); off += (size_t)256 * 9 * 256 * 2;
    const size_t fixed = (off + 255) & ~(size_t)255;

    const size_t MB = 1024u * 1024u;
    // per image: A/G 8MB, P 4MB, F 8MB = 20MB (sr/hr passes reuse A,P)
    int nb = 8;
    while (nb > 1 && fixed + (size_t)nb * 20 * MB > ws_size) nb >>= 1;

    bf16* A = (bf16*)(ws + fixed);                            // (nb,256,256,64)|(nb,128,128,256)
    bf16* P = (bf16*)(ws + fixed + (size_t)nb * 8 * MB);      // (nb,128,128,128)
    bf16* F = (bf16*)(ws + fixed + (size_t)nb * 12 * MB);     // (nb,128,128,256)

    zero_accs_kernel<<<1, 64, 0, stream>>>(accs, zbuf);
    wprep_kernel<<<288, 256, 0, stream>>>(w2, wb2, 64, 128);
    wprep_kernel<<<1152, 256, 0, stream>>>(w3, wb3, 128, 256);
    wprep_kernel<<<2304, 256, 0, stream>>>(w4, wb4, 256, 256);
    mse_kernel<<<2048, 256, 0, stream>>>(sr, hr, accs + 0, 524288);
    ssim_kernel<<<dim3(245, 8), 256, 0, stream>>>(sr, hr, accs + 1);

    for (int b0 = 0; b0 < 8; b0 += nb) {
        // ---- sr pass: features -> F ----
        conv1_kernel<<<dim3(256, nb), 256, 0, stream>>>(sr + (size_t)b0 * 65536, w1, b1, A);
        conv_mfma4<64, 1><<<dim3(16, 8, nb * 2), 256, 0, stream>>>(
            A, wb2, b2, P, 256, 256, 128, zbuf, nullptr, nullptr);
        conv_mfma4<128, 0><<<dim3(8, 4, nb * 4), 256, 0, stream>>>(
            P, wb3, b3, A, 128, 128, 256, zbuf, nullptr, nullptr);
        conv_mfma4<256, 0><<<dim3(8, 4, nb * 4), 256, 0, stream>>>(
            A, wb4, b4, F, 128, 128, 256, zbuf, nullptr, nullptr);
        // ---- hr pass: features, fused perceptual vs F ----
        conv1_kernel<<<dim3(256, nb), 256, 0, stream>>>(hr + (size_t)b0 * 65536, w1, b1, A);
        conv_mfma4<64, 1><<<dim3(16, 8, nb * 2), 256, 0, stream>>>(
            A, wb2, b2, P, 256, 256, 128, zbuf, nullptr, nullptr);
        conv_mfma4<128, 0><<<dim3(8, 4, nb * 4), 256, 0, stream>>>(
            P, wb3, b3, A, 128, 128, 256, zbuf, nullptr, nullptr);
        conv_mfma4<256, 2><<<dim3(8, 4, nb * 4), 256, 0, stream>>>(
            A, wb4, b4, nullptr, 128, 128, 256, zbuf, F, accs + 2);
    }

    finalize_kernel<<<1, 1, 0, stream>>>(accs, out);
}